// Round 1
// baseline (454.979 us; speedup 1.0000x reference)
//
#include <hip/hip_runtime.h>
#include <hip/hip_bf16.h>

// ---------------- ArcFace constants ----------------
#define ARC_S    30.0f
#define ARC_COSM 0.8775825618903728f   // cos(0.5)
#define ARC_SINM 0.4794255386042030f   // sin(0.5)
#define ARC_TH  -0.8775825618903728f   // cos(pi-0.5)
#define ARC_MM   0.2397127693021015f   // sin(pi-0.5)*0.5

#define B_ROWS 512
#define D_DIM  512
#define C_CLS  100000
#define C_PAD  100096                  // 782 * 128

typedef float  floatx4 __attribute__((ext_vector_type(4)));
typedef __bf16 bf16x8  __attribute__((ext_vector_type(8)));

// ---------------------------------------------------------------------------
// Row L2-normalize (row length fixed = 512 floats) -> bf16.
// One wave per row; 4 rows per 256-thread block. Rows >= valid_rows get zeros
// (padding rows of the weight matrix so the GEMM can run an exact 128-grid).
// ---------------------------------------------------------------------------
__global__ __launch_bounds__(256) void normalize_rows_512(
    const float* __restrict__ src, __bf16* __restrict__ dst, int valid_rows)
{
    const int lane = threadIdx.x & 63;
    const int wave = threadIdx.x >> 6;
    const long long row = (long long)blockIdx.x * 4 + wave;

    __bf16* drow = dst + row * D_DIM;

    if (row >= valid_rows) {
        // zero-fill padded rows: one 16B store per lane covers the row
        bf16x8 z;
        #pragma unroll
        for (int i = 0; i < 8; i++) z[i] = (__bf16)0.0f;
        *(bf16x8*)(drow + lane * 8) = z;
        return;
    }

    const float4* rp = (const float4*)(src + row * D_DIM);
    float4 p0 = rp[lane * 2];
    float4 p1 = rp[lane * 2 + 1];

    float ss = p0.x*p0.x + p0.y*p0.y + p0.z*p0.z + p0.w*p0.w
             + p1.x*p1.x + p1.y*p1.y + p1.z*p1.z + p1.w*p1.w;
    #pragma unroll
    for (int m = 32; m >= 1; m >>= 1) ss += __shfl_xor(ss, m, 64);

    const float scale = 1.0f / fmaxf(sqrtf(ss), 1e-12f);

    bf16x8 v;
    v[0] = (__bf16)(p0.x * scale);
    v[1] = (__bf16)(p0.y * scale);
    v[2] = (__bf16)(p0.z * scale);
    v[3] = (__bf16)(p0.w * scale);
    v[4] = (__bf16)(p1.x * scale);
    v[5] = (__bf16)(p1.y * scale);
    v[6] = (__bf16)(p1.z * scale);
    v[7] = (__bf16)(p1.w * scale);
    *(bf16x8*)(drow + lane * 8) = v;
}

// ---------------------------------------------------------------------------
// bf16 MFMA GEMM (M=512, N=100096 padded, K=512) + fused ArcFace epilogue.
// 128x128 tile per block, BK=64, 4 waves (2x2), each wave 4x4 of 16x16x32.
// A: [512,512] row-major bf16 (normalized input)
// W: [C_PAD,512] row-major bf16 (normalized weight) == B^T layout
// ---------------------------------------------------------------------------
#define BM 128
#define BN 128
#define BK 64

__device__ inline void async_load_16B(__bf16* lds, const __bf16* gmem)
{
    __builtin_amdgcn_global_load_lds(
        (const __attribute__((address_space(1))) void*)gmem,
        (__attribute__((address_space(3))) void*)lds,
        16, 0, 0);
}

__global__ __launch_bounds__(256) void gemm_arcface(
    const __bf16* __restrict__ A,
    const __bf16* __restrict__ W,
    const int*    __restrict__ label,
    float*        __restrict__ out)
{
    __shared__ __bf16 As[BM * BK];
    __shared__ __bf16 Bs[BN * BK];
    __shared__ int    sLab[BM];

    const int tid = threadIdx.x;
    const int n0  = blockIdx.x * BN;   // class tile
    const int m0  = blockIdx.y * BM;   // batch tile

    if (tid < BM) sLab[tid] = label[m0 + tid];

    const int lane = tid & 63;
    const int wave = tid >> 6;
    const int wr   = wave >> 1;        // 0..1 (M direction)
    const int wc   = wave & 1;         // 0..1 (N direction)

    floatx4 acc[4][4];
    #pragma unroll
    for (int i = 0; i < 4; i++)
        #pragma unroll
        for (int j = 0; j < 4; j++)
            acc[i][j] = (floatx4)(0.0f);

    const int frow = lane & 15;        // row within 16x16 frag
    const int fk   = (lane >> 4) * 8;  // k offset within 32-chunk

    for (int k0 = 0; k0 < D_DIM; k0 += BK) {
        if (k0) __syncthreads();       // previous tile's reads complete
        // stage A-tile and B-tile: 1024 chunks of 16B each, 4 per thread
        #pragma unroll
        for (int r = 0; r < 4; r++) {
            const int i   = r * 256 + tid;       // chunk index, lane-contiguous
            const int row = i >> 3;
            const int kc  = i & 7;
            async_load_16B(As + i * 8, A + (long long)(m0 + row) * D_DIM + k0 + kc * 8);
            async_load_16B(Bs + i * 8, W + (long long)(n0 + row) * D_DIM + k0 + kc * 8);
        }
        __syncthreads();               // compiler inserts vmcnt(0) drain here

        #pragma unroll
        for (int ks = 0; ks < 2; ks++) {
            bf16x8 a[4], b[4];
            #pragma unroll
            for (int i = 0; i < 4; i++)
                a[i] = *(const bf16x8*)(As + (wr * 64 + i * 16 + frow) * BK + ks * 32 + fk);
            #pragma unroll
            for (int j = 0; j < 4; j++)
                b[j] = *(const bf16x8*)(Bs + (wc * 64 + j * 16 + frow) * BK + ks * 32 + fk);
            #pragma unroll
            for (int i = 0; i < 4; i++)
                #pragma unroll
                for (int j = 0; j < 4; j++)
                    acc[i][j] = __builtin_amdgcn_mfma_f32_16x16x32_bf16(
                        a[i], b[j], acc[i][j], 0, 0, 0);
        }
    }

    // ---- fused ArcFace epilogue ----
    // D layout: row (M) = (lane>>4)*4 + reg, col (N) = lane&15
    const int mrow = (lane >> 4) * 4;
    const int ncol = lane & 15;

    #pragma unroll
    for (int i = 0; i < 4; i++) {
        #pragma unroll
        for (int r = 0; r < 4; r++) {
            const int ml  = wr * 64 + i * 16 + mrow + r;
            const int m   = m0 + ml;
            const int lab = sLab[ml];
            float* orow = out + (long long)m * C_CLS;
            #pragma unroll
            for (int j = 0; j < 4; j++) {
                const int cls = n0 + wc * 64 + j * 16 + ncol;
                if (cls < C_CLS) {
                    float c = fminf(fmaxf(acc[i][j][r], -1.0f), 1.0f);
                    float t = fminf(fmaxf(1.0f - c * c, 1e-9f), 1.0f);
                    float s = sqrtf(t);
                    float phi = c * ARC_COSM - s * ARC_SINM;
                    phi = (c > ARC_TH) ? phi : (c - ARC_MM);
                    float o = ((lab == cls) ? phi : c) * ARC_S;
                    orow[cls] = o;
                }
            }
        }
    }
}

// ---------------------------------------------------------------------------
extern "C" void kernel_launch(void* const* d_in, const int* in_sizes, int n_in,
                              void* d_out, int out_size, void* d_ws, size_t ws_size,
                              hipStream_t stream)
{
    const float* inp    = (const float*)d_in[0];
    const int*   label  = (const int*)d_in[1];
    const float* weight = (const float*)d_in[2];
    float*       out    = (float*)d_out;

    // workspace layout: A_bf16 [512*512], W_bf16 [C_PAD*512]
    __bf16* A = (__bf16*)d_ws;
    __bf16* W = A + (size_t)B_ROWS * D_DIM;

    // K1: normalize input rows (512 rows, 4 rows/block)
    normalize_rows_512<<<B_ROWS / 4, 256, 0, stream>>>(inp, A, B_ROWS);
    // K2: normalize weight rows (+ zero-fill padding to C_PAD)
    normalize_rows_512<<<C_PAD / 4, 256, 0, stream>>>(weight, W, C_CLS);
    // K3: GEMM + ArcFace epilogue
    gemm_arcface<<<dim3(C_PAD / BN, B_ROWS / BM), 256, 0, stream>>>(A, W, label, out);
}

// Round 2
// 444.194 us; speedup vs baseline: 1.0243x; 1.0243x over previous
//
#include <hip/hip_runtime.h>
#include <hip/hip_bf16.h>

// ---------------- ArcFace constants ----------------
#define ARC_S    30.0f
#define ARC_COSM 0.8775825618903728f   // cos(0.5)
#define ARC_SINM 0.4794255386042030f   // sin(0.5)
#define ARC_TH  -0.8775825618903728f   // cos(pi-0.5)
#define ARC_MM   0.2397127693021015f   // sin(pi-0.5)*0.5

#define B_ROWS 512
#define D_DIM  512
#define C_CLS  100000
#define C_PAD  100096                  // 782 * 128

typedef float  floatx4 __attribute__((ext_vector_type(4)));
typedef __bf16 bf16x8  __attribute__((ext_vector_type(8)));

// ---------------------------------------------------------------------------
// Row L2-normalize (row length fixed = 512 floats) -> bf16.
// One wave per row; 4 rows per 256-thread block. Rows >= valid_rows get zeros
// (padding rows of the weight matrix so the GEMM can run an exact 128-grid).
// ---------------------------------------------------------------------------
__global__ __launch_bounds__(256) void normalize_rows_512(
    const float* __restrict__ src, __bf16* __restrict__ dst, int valid_rows)
{
    const int lane = threadIdx.x & 63;
    const int wave = threadIdx.x >> 6;
    const long long row = (long long)blockIdx.x * 4 + wave;

    __bf16* drow = dst + row * D_DIM;

    if (row >= valid_rows) {
        bf16x8 z;
        #pragma unroll
        for (int i = 0; i < 8; i++) z[i] = (__bf16)0.0f;
        *(bf16x8*)(drow + lane * 8) = z;
        return;
    }

    const float4* rp = (const float4*)(src + row * D_DIM);
    float4 p0 = rp[lane * 2];
    float4 p1 = rp[lane * 2 + 1];

    float ss = p0.x*p0.x + p0.y*p0.y + p0.z*p0.z + p0.w*p0.w
             + p1.x*p1.x + p1.y*p1.y + p1.z*p1.z + p1.w*p1.w;
    #pragma unroll
    for (int m = 32; m >= 1; m >>= 1) ss += __shfl_xor(ss, m, 64);

    const float scale = 1.0f / fmaxf(sqrtf(ss), 1e-12f);

    bf16x8 v;
    v[0] = (__bf16)(p0.x * scale);
    v[1] = (__bf16)(p0.y * scale);
    v[2] = (__bf16)(p0.z * scale);
    v[3] = (__bf16)(p0.w * scale);
    v[4] = (__bf16)(p1.x * scale);
    v[5] = (__bf16)(p1.y * scale);
    v[6] = (__bf16)(p1.z * scale);
    v[7] = (__bf16)(p1.w * scale);
    *(bf16x8*)(drow + lane * 8) = v;
}

// ---------------------------------------------------------------------------
// bf16 MFMA GEMM (M=512, N=100096 padded, K=512) + fused ArcFace epilogue.
// 128x128 tile per block, BK=64, 4 waves (2x2), each wave 4x4 of 16x16x32.
// LDS layout XOR-swizzled: slot (row, s) holds gmem k-chunk (s ^ (row&7)).
//   -> fragment reads spread over all 32 banks (was 16-way conflict).
// Grid: x = m-tile (4, fastest) so the 4 blocks sharing one W-tile are
//   dispatch-adjacent -> W read once from HBM, 3x from L2/L3.
// ---------------------------------------------------------------------------
#define BM 128
#define BN 128
#define BK 64

__device__ inline void async_load_16B(__bf16* lds, const __bf16* gmem)
{
    __builtin_amdgcn_global_load_lds(
        (const __attribute__((address_space(1))) void*)gmem,
        (__attribute__((address_space(3))) void*)lds,
        16, 0, 0);
}

__global__ __launch_bounds__(256, 4) void gemm_arcface(
    const __bf16* __restrict__ A,
    const __bf16* __restrict__ W,
    const int*    __restrict__ label,
    float*        __restrict__ out)
{
    __shared__ __bf16 As[BM * BK];
    __shared__ __bf16 Bs[BN * BK];
    __shared__ int    sLab[BM];

    const int tid = threadIdx.x;
    const int m0  = blockIdx.x * BM;   // batch tile (fastest-varying)
    const int n0  = blockIdx.y * BN;   // class tile

    if (tid < BM) sLab[tid] = label[m0 + tid];

    const int lane = tid & 63;
    const int wave = tid >> 6;
    const int wr   = wave >> 1;        // 0..1 (M direction)
    const int wc   = wave & 1;         // 0..1 (N direction)

    floatx4 acc[4][4];
    #pragma unroll
    for (int i = 0; i < 4; i++)
        #pragma unroll
        for (int j = 0; j < 4; j++)
            acc[i][j] = (floatx4)(0.0f);

    const int frow = lane & 15;        // row within 16x16 frag
    const int fch  = lane >> 4;        // k-chunk sub-index 0..3

    for (int k0 = 0; k0 < D_DIM; k0 += BK) {
        if (k0) __syncthreads();       // previous tile's reads complete
        // stage A-tile and B-tile: 1024 chunks of 16B each, 4 per thread.
        // LDS dst stays lane-linear (global_load_lds requirement); the
        // XOR swizzle permutes the gmem source column instead.
        #pragma unroll
        for (int r = 0; r < 4; r++) {
            const int i   = r * 256 + tid;       // chunk index, lane-contiguous
            const int row = i >> 3;
            const int kc  = i & 7;
            const int kcs = kc ^ (row & 7);      // swizzled source chunk
            async_load_16B(As + i * 8, A + (long long)(m0 + row) * D_DIM + k0 + kcs * 8);
            async_load_16B(Bs + i * 8, W + (long long)(n0 + row) * D_DIM + k0 + kcs * 8);
        }
        __syncthreads();               // staging visible (vmcnt(0) drain)

        #pragma unroll
        for (int ks = 0; ks < 2; ks++) {
            const int ch = ks * 4 + fch;         // gmem k-chunk wanted
            bf16x8 a[4], b[4];
            #pragma unroll
            for (int i = 0; i < 4; i++) {
                const int ar = wr * 64 + i * 16 + frow;
                a[i] = *(const bf16x8*)(As + ar * BK + ((ch ^ (ar & 7)) << 3));
            }
            #pragma unroll
            for (int j = 0; j < 4; j++) {
                const int br = wc * 64 + j * 16 + frow;
                b[j] = *(const bf16x8*)(Bs + br * BK + ((ch ^ (br & 7)) << 3));
            }
            #pragma unroll
            for (int i = 0; i < 4; i++)
                #pragma unroll
                for (int j = 0; j < 4; j++)
                    acc[i][j] = __builtin_amdgcn_mfma_f32_16x16x32_bf16(
                        a[i], b[j], acc[i][j], 0, 0, 0);
        }
    }

    // ---- fused ArcFace epilogue ----
    // D layout: row (M) = (lane>>4)*4 + reg, col (N) = lane&15
    const int mrow = (lane >> 4) * 4;
    const int ncol = lane & 15;

    #pragma unroll
    for (int i = 0; i < 4; i++) {
        #pragma unroll
        for (int r = 0; r < 4; r++) {
            const int ml  = wr * 64 + i * 16 + mrow + r;
            const int m   = m0 + ml;
            const int lab = sLab[ml];
            float* orow = out + (long long)m * C_CLS;
            #pragma unroll
            for (int j = 0; j < 4; j++) {
                const int cls = n0 + wc * 64 + j * 16 + ncol;
                if (cls < C_CLS) {
                    float c = fminf(fmaxf(acc[i][j][r], -1.0f), 1.0f);
                    float t = fminf(fmaxf(1.0f - c * c, 1e-9f), 1.0f);
                    float s = sqrtf(t);
                    float phi = c * ARC_COSM - s * ARC_SINM;
                    phi = (c > ARC_TH) ? phi : (c - ARC_MM);
                    float o = ((lab == cls) ? phi : c) * ARC_S;
                    orow[cls] = o;
                }
            }
        }
    }
}

// ---------------------------------------------------------------------------
extern "C" void kernel_launch(void* const* d_in, const int* in_sizes, int n_in,
                              void* d_out, int out_size, void* d_ws, size_t ws_size,
                              hipStream_t stream)
{
    const float* inp    = (const float*)d_in[0];
    const int*   label  = (const int*)d_in[1];
    const float* weight = (const float*)d_in[2];
    float*       out    = (float*)d_out;

    // workspace layout: A_bf16 [512*512], W_bf16 [C_PAD*512]
    __bf16* A = (__bf16*)d_ws;
    __bf16* W = A + (size_t)B_ROWS * D_DIM;

    // K1: normalize input rows (512 rows, 4 rows/block)
    normalize_rows_512<<<B_ROWS / 4, 256, 0, stream>>>(inp, A, B_ROWS);
    // K2: normalize weight rows (+ zero-fill padding to C_PAD)
    normalize_rows_512<<<C_PAD / 4, 256, 0, stream>>>(weight, W, C_CLS);
    // K3: GEMM + ArcFace epilogue (m-tile fastest for W-tile L2 reuse)
    gemm_arcface<<<dim3(B_ROWS / BM, C_PAD / BN), 256, 0, stream>>>(A, W, label, out);
}

// Round 3
// 436.602 us; speedup vs baseline: 1.0421x; 1.0174x over previous
//
#include <hip/hip_runtime.h>
#include <hip/hip_bf16.h>

// ---------------- ArcFace constants ----------------
#define ARC_S    30.0f
#define ARC_COSM 0.8775825618903728f   // cos(0.5)
#define ARC_SINM 0.4794255386042030f   // sin(0.5)
#define ARC_TH  -0.8775825618903728f   // cos(pi-0.5)
#define ARC_MM   0.2397127693021015f   // sin(pi-0.5)*0.5

#define B_ROWS 512
#define D_DIM  512
#define C_CLS  100000
#define C_PAD  100096                  // 782 * 128

typedef float  floatx4 __attribute__((ext_vector_type(4)));
typedef __bf16 bf16x8  __attribute__((ext_vector_type(8)));

// ---------------------------------------------------------------------------
// Row L2-normalize (row length fixed = 512 floats) -> bf16.
// One wave per row; 4 rows per 256-thread block. Rows >= valid_rows get zeros.
// ---------------------------------------------------------------------------
__global__ __launch_bounds__(256) void normalize_rows_512(
    const float* __restrict__ src, __bf16* __restrict__ dst, int valid_rows)
{
    const int lane = threadIdx.x & 63;
    const int wave = threadIdx.x >> 6;
    const long long row = (long long)blockIdx.x * 4 + wave;

    __bf16* drow = dst + row * D_DIM;

    if (row >= valid_rows) {
        bf16x8 z;
        #pragma unroll
        for (int i = 0; i < 8; i++) z[i] = (__bf16)0.0f;
        *(bf16x8*)(drow + lane * 8) = z;
        return;
    }

    const float4* rp = (const float4*)(src + row * D_DIM);
    float4 p0 = rp[lane * 2];
    float4 p1 = rp[lane * 2 + 1];

    float ss = p0.x*p0.x + p0.y*p0.y + p0.z*p0.z + p0.w*p0.w
             + p1.x*p1.x + p1.y*p1.y + p1.z*p1.z + p1.w*p1.w;
    #pragma unroll
    for (int m = 32; m >= 1; m >>= 1) ss += __shfl_xor(ss, m, 64);

    const float scale = 1.0f / fmaxf(sqrtf(ss), 1e-12f);

    bf16x8 v;
    v[0] = (__bf16)(p0.x * scale);
    v[1] = (__bf16)(p0.y * scale);
    v[2] = (__bf16)(p0.z * scale);
    v[3] = (__bf16)(p0.w * scale);
    v[4] = (__bf16)(p1.x * scale);
    v[5] = (__bf16)(p1.y * scale);
    v[6] = (__bf16)(p1.z * scale);
    v[7] = (__bf16)(p1.w * scale);
    *(bf16x8*)(drow + lane * 8) = v;
}

// ---------------------------------------------------------------------------
// bf16 MFMA GEMM (M=512, N=100096 padded, K=512) + fused ArcFace epilogue.
// 256x128 tile per block, BK=64, 512 threads = 8 waves (4M x 2N),
// each wave 64x64 = 4x4 frags of 16x16x32 (64 acc floats/thread).
// Rationale: total staged bytes = 512KB*(N/BN) + 102.4MB*(M/BM);
//   256x128 @ 512thr cuts it 800->605 MB vs 128x128 @ 256thr.
// LDS XOR-swizzled (slot kc holds gmem chunk kc^(row&7)) -> 0 bank conflicts.
// Grid swizzle: blocks b and b+8 (same XCD under %8 round-robin) cover the
//   SAME n-tile with the two m-tiles -> 2nd W-tile read hits that XCD's L2.
// ---------------------------------------------------------------------------
#define BM 256
#define BN 128
#define BK 64
#define N_TILES 782   // C_PAD / BN
#define GRID_B  1568  // 16 * ceil(N_TILES*2 / 16)

__device__ inline void async_load_16B(__bf16* lds, const __bf16* gmem)
{
    __builtin_amdgcn_global_load_lds(
        (const __attribute__((address_space(1))) void*)gmem,
        (__attribute__((address_space(3))) void*)lds,
        16, 0, 0);
}

__global__ __launch_bounds__(512, 4) void gemm_arcface(
    const __bf16* __restrict__ A,
    const __bf16* __restrict__ W,
    const int*    __restrict__ label,
    float*        __restrict__ out)
{
    // XCD-aware swizzle: groups of 16 consecutive ids cover 8 n-tiles x 2
    // m-tiles such that the m-pair ids differ by exactly 8 (same XCD).
    const int b  = blockIdx.x;
    const int nt = (b & 7) + 8 * (b >> 4);
    const int mt = (b >> 3) & 1;
    if (nt >= N_TILES) return;   // uniform tail guard (8 idle blocks)

    __shared__ __bf16 As[BM * BK];
    __shared__ __bf16 Bs[BN * BK];
    __shared__ int    sLab[BM];

    const int tid = threadIdx.x;
    const int m0  = mt * BM;
    const int n0  = nt * BN;

    if (tid < BM) sLab[tid] = label[m0 + tid];

    const int lane = tid & 63;
    const int wave = tid >> 6;
    const int wr   = wave >> 1;        // 0..3 (M direction, 64 rows each)
    const int wc   = wave & 1;         // 0..1 (N direction, 64 cols each)

    floatx4 acc[4][4];
    #pragma unroll
    for (int i = 0; i < 4; i++)
        #pragma unroll
        for (int j = 0; j < 4; j++)
            acc[i][j] = (floatx4)(0.0f);

    const int frow = lane & 15;        // row within 16x16 frag
    const int fch  = lane >> 4;        // k-chunk sub-index 0..3

    for (int k0 = 0; k0 < D_DIM; k0 += BK) {
        if (k0) __syncthreads();       // previous tile's reads complete
        // stage A (2048 chunks) + B (1024 chunks) of 16B; 6 per thread.
        // LDS dst stays lane-linear (global_load_lds requirement); XOR
        // swizzle permutes the gmem source column instead.
        #pragma unroll
        for (int r = 0; r < 4; r++) {
            const int i   = r * 512 + tid;
            const int row = i >> 3;
            const int kc  = i & 7;
            const int kcs = kc ^ (row & 7);
            async_load_16B(As + i * 8, A + (long long)(m0 + row) * D_DIM + k0 + kcs * 8);
        }
        #pragma unroll
        for (int r = 0; r < 2; r++) {
            const int i   = r * 512 + tid;
            const int row = i >> 3;
            const int kc  = i & 7;
            const int kcs = kc ^ (row & 7);
            async_load_16B(Bs + i * 8, W + (long long)(n0 + row) * D_DIM + k0 + kcs * 8);
        }
        __syncthreads();               // staging visible (vmcnt(0) drain)

        #pragma unroll
        for (int ks = 0; ks < 2; ks++) {
            const int ch = ks * 4 + fch;         // gmem k-chunk wanted
            bf16x8 a[4], bb[4];
            #pragma unroll
            for (int i = 0; i < 4; i++) {
                const int ar = wr * 64 + i * 16 + frow;
                a[i] = *(const bf16x8*)(As + ar * BK + ((ch ^ (ar & 7)) << 3));
            }
            #pragma unroll
            for (int j = 0; j < 4; j++) {
                const int br = wc * 64 + j * 16 + frow;
                bb[j] = *(const bf16x8*)(Bs + br * BK + ((ch ^ (br & 7)) << 3));
            }
            #pragma unroll
            for (int i = 0; i < 4; i++)
                #pragma unroll
                for (int j = 0; j < 4; j++)
                    acc[i][j] = __builtin_amdgcn_mfma_f32_16x16x32_bf16(
                        a[i], bb[j], acc[i][j], 0, 0, 0);
        }
    }

    // ---- fused ArcFace epilogue ----
    // D layout: row (M) = (lane>>4)*4 + reg, col (N) = lane&15
    const int mrow = (lane >> 4) * 4;
    const int ncol = lane & 15;

    #pragma unroll
    for (int i = 0; i < 4; i++) {
        #pragma unroll
        for (int r = 0; r < 4; r++) {
            const int ml  = wr * 64 + i * 16 + mrow + r;
            const int m   = m0 + ml;
            const int lab = sLab[ml];
            float* orow = out + (long long)m * C_CLS;
            #pragma unroll
            for (int j = 0; j < 4; j++) {
                const int cls = n0 + wc * 64 + j * 16 + ncol;
                if (cls < C_CLS) {
                    float c = fminf(fmaxf(acc[i][j][r], -1.0f), 1.0f);
                    float t = fminf(fmaxf(1.0f - c * c, 1e-9f), 1.0f);
                    float s = sqrtf(t);
                    float phi = c * ARC_COSM - s * ARC_SINM;
                    phi = (c > ARC_TH) ? phi : (c - ARC_MM);
                    float o = ((lab == cls) ? phi : c) * ARC_S;
                    orow[cls] = o;
                }
            }
        }
    }
}

// ---------------------------------------------------------------------------
extern "C" void kernel_launch(void* const* d_in, const int* in_sizes, int n_in,
                              void* d_out, int out_size, void* d_ws, size_t ws_size,
                              hipStream_t stream)
{
    const float* inp    = (const float*)d_in[0];
    const int*   label  = (const int*)d_in[1];
    const float* weight = (const float*)d_in[2];
    float*       out    = (float*)d_out;

    // workspace layout: A_bf16 [512*512], W_bf16 [C_PAD*512]
    __bf16* A = (__bf16*)d_ws;
    __bf16* W = A + (size_t)B_ROWS * D_DIM;

    // K1: normalize input rows (512 rows, 4 rows/block)
    normalize_rows_512<<<B_ROWS / 4, 256, 0, stream>>>(inp, A, B_ROWS);
    // K2: normalize weight rows (+ zero-fill padding to C_PAD)
    normalize_rows_512<<<C_PAD / 4, 256, 0, stream>>>(weight, W, C_CLS);
    // K3: GEMM + ArcFace epilogue (XCD-paired grid, 256x128 tiles)
    gemm_arcface<<<GRID_B, 512, 0, stream>>>(A, W, label, out);
}